// Round 24
// baseline (85.757 us; speedup 1.0000x reference)
//
#include <hip/hip_runtime.h>
#include <hip/hip_bf16.h>
#include <math.h>

#define SEQ 2048
#define DM 768
#define NH 12
#define HD 64
#define NB 2
#define NT (NB*SEQ)      // 4096 tokens
#define E3 (3*DM)        // 2304

using short4v = __attribute__((ext_vector_type(4))) short;
using short8v = __attribute__((ext_vector_type(8))) short;
using floatx4 = __attribute__((ext_vector_type(4))) float;
using int4v   = __attribute__((ext_vector_type(4))) int;

#if __has_builtin(__builtin_amdgcn_exp2f)
#define EXPFN(x) __builtin_amdgcn_exp2f(x)
#define QSCALE 0.1803368801111244f   /* 0.125 * log2(e) : scores in log2 domain */
#else
#define EXPFN(x) __expf(x)
#define QSCALE 0.125f
#endif

static __device__ __forceinline__ short bfb(float f) {
  union { __hip_bfloat16 h; short s; } u;
  u.h = __float2bfloat16(f);
  return u.s;
}

// async global->LDS, 16 bytes per lane. lds must be wave-uniform.
static __device__ __forceinline__ void gload_lds16(const __hip_bfloat16* g, __hip_bfloat16* lds) {
  __builtin_amdgcn_global_load_lds(
      (const __attribute__((address_space(1))) unsigned int*)g,
      (__attribute__((address_space(3))) unsigned int*)lds, 16, 0, 0);
}

// K granule swizzle (16B granules, 8 per 128B row): rows 8a+b -> (a+2b)&7
static __device__ __forceinline__ int swzg(int row) {
  return (((row >> 3) & 3) + 2 * (row & 3)) & 7;
}

// ---------------- fused fp32->bf16 convert (x, Wq, Wo) + rope table + queue reset ----------------
#define XN4 (NT * DM / 4)          // 786432
#define WQN4 (E3 * DM / 4)         // 442368
#define WON4 (DM * DM / 4)         // 147456
#define CVT_N (XN4 + WQN4 + WON4)  // 1376256
__global__ void cvt3_rope(const float* __restrict__ x, const float* __restrict__ wq,
                          const float* __restrict__ wo,
                          __hip_bfloat16* __restrict__ xb, __hip_bfloat16* __restrict__ wqb,
                          __hip_bfloat16* __restrict__ wob, float2* __restrict__ rcs,
                          int* __restrict__ qcnt) {
  int i = blockIdx.x * blockDim.x + threadIdx.x;
  if (blockIdx.x == 0 && threadIdx.x < 8) qcnt[threadIdx.x] = 0;  // per-XCD LPT queues
  if (i >= CVT_N) {
    int idx = i - CVT_N;
    if (idx < SEQ * 32) {
      int pos = idx >> 5, j = idx & 31;
      float freq = __expf(-(float)j * (logf(10000.0f) / 32.0f));
      float ang = (float)pos * freq;
      rcs[idx] = make_float2(cosf(ang), sinf(ang));
    }
    return;
  }
  const float* src;
  __hip_bfloat16* dst;
  int k;
  if (i < XN4) { src = x; dst = xb; k = i; }
  else if (i < XN4 + WQN4) { src = wq; dst = wqb; k = i - XN4; }
  else { src = wo; dst = wob; k = i - XN4 - WQN4; }
  floatx4 v = ((const floatx4*)src)[k];
  short4v o;
  o[0] = bfb(v[0]); o[1] = bfb(v[1]); o[2] = bfb(v[2]); o[3] = bfb(v[3]);
  ((short4v*)dst)[k] = o;
}

// ---------------- QKV GEMM v4: 64x128 tile, BK=64, double-buffered (R19) ----------------
__global__ __launch_bounds__(256) void qkv_gemm_rope(
    const __hip_bfloat16* __restrict__ Wq,
    const __hip_bfloat16* __restrict__ Xb,
    const int* __restrict__ tpos,
    const float2* __restrict__ rcs,
    __hip_bfloat16* __restrict__ Qb, __hip_bfloat16* __restrict__ Kb,
    __hip_bfloat16* __restrict__ Vt)
{
  __shared__ __align__(16) __hip_bfloat16 As[2][64 * 64];    // 8KB each
  __shared__ __align__(16) __hip_bfloat16 Bs[2][128 * 64];   // 16KB each
  const int tid = threadIdx.x;
  const int lane = tid & 63, w = tid >> 6;
  const int c = lane & 15, g = lane >> 4;
  const int wr = w >> 1, wc = w & 1;
  const int bid = blockIdx.x;
  const int xcd = bid & 7, i_ = bid >> 3;        // 144 per XCD
  const int nb = xcd * 4 + (i_ & 3), mb = i_ >> 2;  // nb 0..31, mb 0..35
  const int m0 = mb * 64, n0 = nb * 128;
  const int srow = tid >> 3, sslot = tid & 7;    // 32 rows x 8 slots per call

#define QKV_STAGE(K0_, AD, BD)                                                      \
  do {                                                                              \
    _Pragma("unroll")                                                               \
    for (int j = 0; j < 2; ++j) {                                                   \
      const int row = j * 32 + srow;                                                \
      const int gs = (sslot ^ (row & 7)) * 8;                                       \
      gload_lds16(Wq + (size_t)(m0 + row) * DM + (K0_) + gs, (AD) + j * 2048 + w * 512); \
    }                                                                               \
    _Pragma("unroll")                                                               \
    for (int j = 0; j < 4; ++j) {                                                   \
      const int row = j * 32 + srow;                                                \
      const int gs = (sslot ^ (row & 7)) * 8;                                       \
      gload_lds16(Xb + (size_t)(n0 + row) * DM + (K0_) + gs, (BD) + j * 2048 + w * 512); \
    }                                                                               \
  } while (0)

  floatx4 acc[2][4] = {};
  QKV_STAGE(0, As[0], Bs[0]);
  int cb = 0;
  for (int k0 = 0; k0 < DM; k0 += 64) {
    if (k0 + 64 < DM) QKV_STAGE(k0 + 64, As[cb ^ 1], Bs[cb ^ 1]);
    __syncthreads();   // drains stage(k0) — issued one full step ago
#pragma unroll
    for (int kk = 0; kk < 2; ++kk) {
      short8v a[2], b[4];
#pragma unroll
      for (int i = 0; i < 2; ++i) {
        const int row = wr * 32 + i * 16 + c;
        a[i] = *(const short8v*)&As[cb][row * 64 + (((kk * 4 + g) ^ (row & 7)) * 8)];
      }
#pragma unroll
      for (int j = 0; j < 4; ++j) {
        const int row = wc * 64 + j * 16 + c;
        b[j] = *(const short8v*)&Bs[cb][row * 64 + (((kk * 4 + g) ^ (row & 7)) * 8)];
      }
#pragma unroll
      for (int i = 0; i < 2; ++i)
#pragma unroll
        for (int j = 0; j < 4; ++j)
          acc[i][j] = __builtin_amdgcn_mfma_f32_16x16x32_bf16(a[i], b[j], acc[i][j], 0, 0, 0);
    }
    __syncthreads();   // buf[cb] consumed -> reusable for the stage in flight
    cb ^= 1;
  }
#undef QKV_STAGE
#pragma unroll
  for (int i = 0; i < 2; ++i) {
    const int e0 = m0 + wr * 32 + i * 16 + 4 * g;
    const int jj = (e0 & 63) >> 1;
#pragma unroll
    for (int j = 0; j < 4; ++j) {
      const int t = n0 + wc * 64 + j * 16 + c;
      const int b_ = t >> 11, s = t & (SEQ - 1);
      float v0 = acc[i][j][0], v1 = acc[i][j][1], v2 = acc[i][j][2], v3 = acc[i][j][3];
      if (e0 < 2 * DM) {
        const int pos = tpos[t];
        const float2 cs0 = rcs[pos * 32 + jj];
        const float2 cs1 = rcs[pos * 32 + jj + 1];
        const float n0v = v0 * cs0.x - v1 * cs0.y, n1v = v0 * cs0.y + v1 * cs0.x;
        const float n2v = v2 * cs1.x - v3 * cs1.y, n3v = v2 * cs1.y + v3 * cs1.x;
        v0 = n0v; v1 = n1v; v2 = n2v; v3 = n3v;
      }
      if (e0 < DM) {
        const int h = e0 >> 6, d = e0 & 63;
        short4v pk;
        pk[0] = bfb(v0 * QSCALE); pk[1] = bfb(v1 * QSCALE);
        pk[2] = bfb(v2 * QSCALE); pk[3] = bfb(v3 * QSCALE);
        *(short4v*)&Qb[(((size_t)(b_ * NH + h) * SEQ) + s) * HD + d] = pk;
      } else if (e0 < 2 * DM) {
        const int e = e0 - DM, h = e >> 6, d = e & 63;
        short4v pk;
        pk[0] = bfb(v0); pk[1] = bfb(v1); pk[2] = bfb(v2); pk[3] = bfb(v3);
        *(short4v*)&Kb[(((size_t)(b_ * NH + h) * SEQ) + s) * HD + d] = pk;
      } else {
        const int e = e0 - 2 * DM, h = e >> 6, d = e & 63;
        const size_t base = ((size_t)(b_ * NH + h) * HD + d) * SEQ + s;
        Vt[base]           = __float2bfloat16(v0);
        Vt[base + SEQ]     = __float2bfloat16(v1);
        Vt[base + 2 * SEQ] = __float2bfloat16(v2);
        Vt[base + 3 * SEQ] = __float2bfloat16(v3);
      }
    }
  }
}

// ---------------- fused causal flash attention v15: l-sum via MFMA ----------------
// v13 structure (8 waves x 16 q-rows, KVBLK=128, LPT queue, setprio, peel);
// change: softmax denominator l computed on the MATRIX pipe — one extra
// mfma(A=ones, B=pf1, acc_l) per sub-block replaces 16 serial VALU adds and
// the end-of-task cross-lane shuffles (C-layout: col = lane&15 = q-row, all
// regs equal). exp2(-inf)=0 keeps masked keys at zero contribution.
__global__ __launch_bounds__(512) void attn_fused(
    const __hip_bfloat16* __restrict__ Qb,
    const __hip_bfloat16* __restrict__ Kb,
    const __hip_bfloat16* __restrict__ Vt,
    __hip_bfloat16* __restrict__ Cx,
    int* __restrict__ qcnt)
{
  __shared__ __align__(16) __hip_bfloat16 Ks[2][128 * 64];  // 16KB each
  __shared__ __align__(16) __hip_bfloat16 Vs[2][64 * 128];  // V^T: [d][kt], 16KB each
  __shared__ int task_s;
  const int tid = threadIdx.x;
  const int lane = tid & 63, w = tid >> 6;          // 8 waves
  const int c = lane & 15, g = lane >> 4;
  const int xcd = blockIdx.x & 7;
  const int kr1 = 8 * (c >> 2) + (c & 3);           // permuted A-row -> kt_local
  const int ksr = w * 8 + (lane >> 3), kss = lane & 7;     // K stage: rows +64*j
  const int vsr = w * 4 + (lane >> 4), vss = lane & 15;    // V stage: rows +32*j
  const short8v onesv = {0x3F80, 0x3F80, 0x3F80, 0x3F80,
                         0x3F80, 0x3F80, 0x3F80, 0x3F80};  // bf16 1.0 x8

  for (;;) {
    if (tid == 0) task_s = atomicAdd(&qcnt[xcd], 1);
    __syncthreads();
    const int task = task_s;
    if (task >= 48) return;
    const int qG = 15 - task / 3;                   // descending size (LPT)
    const int bh = xcd + 8 * (task % 3);
    const int KBmax = qG;                           // kb = 0..qG (128 keys each)
    const __hip_bfloat16* Qh = Qb + (size_t)bh * SEQ * HD;
    const __hip_bfloat16* Kh = Kb + (size_t)bh * SEQ * HD;
    const __hip_bfloat16* Vh = Vt + (size_t)bh * HD * SEQ;
    const int q1 = qG * 128 + w * 16 + c;           // absolute q-row of this lane
    const int qrl32 = (w & 1) * 16 + c;             // row within the diagonal 32-key window
    const int sdiag = w >> 1;                       // wave's diagonal sub-block (in kb==KBmax)
    const short8v qf10 = *(const short8v*)&Qh[(size_t)q1 * HD + g * 8];
    const short8v qf11 = *(const short8v*)&Qh[(size_t)q1 * HD + 32 + g * 8];
    floatx4 o1[4] = {};
    floatx4 acc_l = {};                             // l per q-row (col c), all regs equal

#define STAGE_KV(KB_, KSD, VSD)                                                      \
    do {                                                                             \
      _Pragma("unroll")                                                              \
      for (int j = 0; j < 2; ++j) {                                                  \
        const int kr = j * 64 + ksr;                                                 \
        gload_lds16(Kh + (size_t)((KB_) * 128 + kr) * HD + ((kss ^ swzg(kr)) * 8),   \
                    (KSD) + j * 4096 + w * 512);                                     \
        const int vr = j * 32 + vsr;                                                 \
        gload_lds16(Vh + (size_t)vr * SEQ + (KB_) * 128 + ((vss ^ (vr & 15)) * 8),   \
                    (VSD) + j * 4096 + w * 512);                                     \
      }                                                                              \
    } while (0)

// one 32-key sub-block: QK (setprio-wrapped), optional mask, exp, PV + l-MFMA
#define SUBBLK(S_, DO_MASK)                                                          \
    do {                                                                             \
      const int r0 = (S_) * 32 + kr1, r1 = r0 + 4;                                   \
      const int z0 = swzg(r0), z1 = swzg(r1);                                        \
      const short8v a00 = *(const short8v*)&Kt[r0 * 64 + ((g ^ z0) * 8)];            \
      const short8v a01 = *(const short8v*)&Kt[r0 * 64 + (((4 + g) ^ z0) * 8)];      \
      const short8v a10 = *(const short8v*)&Kt[r1 * 64 + ((g ^ z1) * 8)];            \
      const short8v a11 = *(const short8v*)&Kt[r1 * 64 + (((4 + g) ^ z1) * 8)];      \
      short8v vf[4];                                                                 \
      _Pragma("unroll")                                                              \
      for (int f = 0; f < 4; ++f) {                                                  \
        const int rv = f * 16 + c;                                                   \
        vf[f] = *(const short8v*)&Vb[rv * 128 + ((((S_) * 4 + g) ^ (rv & 15)) * 8)]; \
      }                                                                              \
      floatx4 s1a = {}, s1b = {};                                                    \
      __builtin_amdgcn_s_setprio(1);                                                 \
      s1a = __builtin_amdgcn_mfma_f32_16x16x32_bf16(a00, qf10, s1a, 0, 0, 0);        \
      s1a = __builtin_amdgcn_mfma_f32_16x16x32_bf16(a01, qf11, s1a, 0, 0, 0);        \
      s1b = __builtin_amdgcn_mfma_f32_16x16x32_bf16(a10, qf10, s1b, 0, 0, 0);        \
      s1b = __builtin_amdgcn_mfma_f32_16x16x32_bf16(a11, qf11, s1b, 0, 0, 0);        \
      __builtin_amdgcn_s_setprio(0);                                                 \
      if (DO_MASK) {                                                                 \
        _Pragma("unroll")                                                            \
        for (int r = 0; r < 4; ++r) {                                                \
          if (8 * g + r > qrl32) s1a[r] = -INFINITY;                                 \
          if (8 * g + r + 4 > qrl32) s1b[r] = -INFINITY;                             \
        }                                                                            \
      }                                                                              \
      short8v pf1;                                                                   \
      _Pragma("unroll")                                                              \
      for (int r = 0; r < 4; ++r) {                                                  \
        pf1[r] = bfb(EXPFN(s1a[r]));                                                 \
        pf1[r + 4] = bfb(EXPFN(s1b[r]));                                             \
      }                                                                              \
      __builtin_amdgcn_s_setprio(1);                                                 \
      o1[0] = __builtin_amdgcn_mfma_f32_16x16x32_bf16(vf[0], pf1, o1[0], 0, 0, 0);   \
      o1[1] = __builtin_amdgcn_mfma_f32_16x16x32_bf16(vf[1], pf1, o1[1], 0, 0, 0);   \
      o1[2] = __builtin_amdgcn_mfma_f32_16x16x32_bf16(vf[2], pf1, o1[2], 0, 0, 0);   \
      o1[3] = __builtin_amdgcn_mfma_f32_16x16x32_bf16(vf[3], pf1, o1[3], 0, 0, 0);   \
      acc_l = __builtin_amdgcn_mfma_f32_16x16x32_bf16(onesv, pf1, acc_l, 0, 0, 0);   \
      __builtin_amdgcn_s_setprio(0);                                                 \
    } while (0)

    STAGE_KV(0, Ks[0], Vs[0]);
    __syncthreads();
    int cb = 0;
    for (int kb = 0; kb <= KBmax; ++kb) {
      if (kb < KBmax) STAGE_KV(kb + 1, Ks[cb ^ 1], Vs[cb ^ 1]);
      {
        const __hip_bfloat16* Kt = Ks[cb];
        const __hip_bfloat16* Vb = Vs[cb];
        if (kb < KBmax) {
          // fast path: every sub-block fully causal for every wave — branch-free.
          SUBBLK(0, false);
          SUBBLK(1, false);
          SUBBLK(2, false);
          SUBBLK(3, false);
        } else {
          // tail: wave w computes sub-blocks s < sdiag unmasked, s == sdiag masked.
#pragma unroll
          for (int s = 0; s < 4; ++s) {
            if (s < sdiag) SUBBLK(s, false);
            else if (s == sdiag) SUBBLK(s, true);
          }
        }
      }
      __syncthreads();
      cb ^= 1;
    }
#undef SUBBLK
#undef STAGE_KV

    const float inv1 = 1.0f / acc_l[0];   // all rows/regs hold the same column-sum
    const int bb = bh / NH, h = bh - bb * NH;
    const size_t trow1 = ((size_t)bb * SEQ + q1) * DM + (size_t)h * HD;
#pragma unroll
    for (int f = 0; f < 4; ++f) {
      short4v pk1;
#pragma unroll
      for (int r = 0; r < 4; ++r) pk1[r] = bfb(o1[f][r] * inv1);
      *(short4v*)&Cx[trow1 + f * 16 + 4 * g] = pk1;
    }
  }
}

// ---------------- output GEMM v3: 64x128 tile, BK=64, double-buffered (R19) ----------------
__global__ __launch_bounds__(256) void out_gemm(
    const __hip_bfloat16* __restrict__ Wo,
    const __hip_bfloat16* __restrict__ Cx,
    float* __restrict__ out)
{
  __shared__ __align__(16) __hip_bfloat16 As[2][64 * 64];    // 8KB each
  __shared__ __align__(16) __hip_bfloat16 Bs[2][128 * 64];   // 16KB each
  const int tid = threadIdx.x;
  const int lane = tid & 63, w = tid >> 6;
  const int c = lane & 15, g = lane >> 4;
  const int wr = w >> 1, wc = w & 1;
  const int bid = blockIdx.x;
  const int xcd = bid & 7, i_ = bid >> 3;        // 48 per XCD
  const int nb = xcd * 4 + (i_ & 3), mb = i_ >> 2;  // nb 0..31 (t), mb 0..11 (e)
  const int m0 = mb * 64, n0 = nb * 128;
  const int srow = tid >> 3, sslot = tid & 7;

#define OUT_STAGE(K0_, AD, BD)                                                      \
  do {                                                                              \
    _Pragma("unroll")                                                               \
    for (int j = 0; j < 2; ++j) {                                                   \
      const int row = j * 32 + srow;                                                \
      const int gs = (sslot ^ (row & 7)) * 8;                                       \
      gload_lds16(Wo + (size_t)(m0 + row) * DM + (K0_) + gs, (AD) + j * 2048 + w * 512); \
    }                                                                               \
    _Pragma("unroll")                                                               \
    for (int j = 0; j < 4; ++j) {                                                   \
      const int row = j * 32 + srow;                                                \
      const int gs = (sslot ^ (row & 7)) * 8;                                       \
      gload_lds16(Cx + (size_t)(n0 + row) * DM + (K0_) + gs, (BD) + j * 2048 + w * 512); \
    }                                                                               \
  } while (0)

  floatx4 acc[2][4] = {};
  OUT_STAGE(0, As[0], Bs[0]);
  int cb = 0;
  for (int k0 = 0; k0 < DM; k0 += 64) {
    if (k0 + 64 < DM) OUT_STAGE(k0 + 64, As[cb ^ 1], Bs[cb ^ 1]);
    __syncthreads();
#pragma unroll
    for (int kk = 0; kk < 2; ++kk) {
      short8v a[2], b[4];
#pragma unroll
      for (int i = 0; i < 2; ++i) {
        const int row = wr * 32 + i * 16 + c;
        a[i] = *(const short8v*)&As[cb][row * 64 + (((kk * 4 + g) ^ (row & 7)) * 8)];
      }
#pragma unroll
      for (int j = 0; j < 4; ++j) {
        const int row = wc * 64 + j * 16 + c;
        b[j] = *(const short8v*)&Bs[cb][row * 64 + (((kk * 4 + g) ^ (row & 7)) * 8)];
      }
#pragma unroll
      for (int i = 0; i < 2; ++i)
#pragma unroll
        for (int j = 0; j < 4; ++j)
          acc[i][j] = __builtin_amdgcn_mfma_f32_16x16x32_bf16(a[i], b[j], acc[i][j], 0, 0, 0);
    }
    __syncthreads();
    cb ^= 1;
  }
#undef OUT_STAGE
#pragma unroll
  for (int i = 0; i < 2; ++i) {
    const int e0 = m0 + wr * 32 + i * 16 + 4 * g;
#pragma unroll
    for (int j = 0; j < 4; ++j) {
      const int t = n0 + wc * 64 + j * 16 + c;
      *(floatx4*)&out[(size_t)t * DM + e0] = acc[i][j];
    }
  }
}

extern "C" void kernel_launch(void* const* d_in, const int* in_sizes, int n_in,
                              void* d_out, int out_size, void* d_ws, size_t ws_size,
                              hipStream_t stream) {
  const float* x    = (const float*)d_in[0];
  const int*   tpos = (const int*)d_in[1];
  const float* Wq   = (const float*)d_in[2];
  const float* Wo   = (const float*)d_in[3];
  float* out = (float*)d_out;

  const size_t QKV_BYTES = (size_t)NB * NH * SEQ * HD * 2;  // 6,291,456
  const size_t REQUIRED = 4 * QKV_BYTES;                    // 25,165,824
  if (ws_size < REQUIRED) return;

  char* ws = (char*)d_ws;
  __hip_bfloat16* Qb = (__hip_bfloat16*)(ws);
  __hip_bfloat16* Kb = (__hip_bfloat16*)(ws + QKV_BYTES);
  __hip_bfloat16* Vt = (__hip_bfloat16*)(ws + 2 * QKV_BYTES);
  __hip_bfloat16* Cx = (__hip_bfloat16*)(ws + 3 * QKV_BYTES);
  __hip_bfloat16* xb = (__hip_bfloat16*)(ws + 3 * QKV_BYTES);   // aliases Cx (dead before attn)
  char* ob = (char*)d_out;   // d_out-head scratch, all dead before out_gemm overwrites
  float2* rcs = (float2*)(ob);                                           // 512KB
  __hip_bfloat16* wqb = (__hip_bfloat16*)(ob + (size_t)SEQ * 32 * 8);    // 3.54MB
  __hip_bfloat16* wob = (__hip_bfloat16*)(ob + (size_t)SEQ * 32 * 8 + (size_t)E3 * DM * 2);  // 1.18MB
  int* qcnt = (int*)(ob + (size_t)SEQ * 32 * 8 + (size_t)E3 * DM * 2 + (size_t)DM * DM * 2); // 32B

  const int TOT_N = CVT_N + SEQ * 32;
  cvt3_rope<<<dim3((TOT_N + 255) / 256), dim3(256), 0, stream>>>(x, Wq, Wo, xb, wqb, wob, rcs, qcnt);
  qkv_gemm_rope<<<dim3(1152), dim3(256), 0, stream>>>(wqb, xb, tpos, rcs, Qb, Kb, Vt);
  attn_fused<<<dim3(512), dim3(512), 0, stream>>>(Qb, Kb, Vt, Cx, qcnt);
  out_gemm<<<dim3(384), dim3(256), 0, stream>>>(wob, Cx, out);
}

// Round 25
// 82.871 us; speedup vs baseline: 1.0348x; 1.0348x over previous
//
#include <hip/hip_runtime.h>
#include <hip/hip_bf16.h>
#include <math.h>

#define SEQ 2048
#define DM 768
#define NH 12
#define HD 64
#define NB 2
#define NT (NB*SEQ)      // 4096 tokens
#define E3 (3*DM)        // 2304

using short4v = __attribute__((ext_vector_type(4))) short;
using short8v = __attribute__((ext_vector_type(8))) short;
using floatx4 = __attribute__((ext_vector_type(4))) float;
using int4v   = __attribute__((ext_vector_type(4))) int;

#if __has_builtin(__builtin_amdgcn_exp2f)
#define EXPFN(x) __builtin_amdgcn_exp2f(x)
#define QSCALE 0.1803368801111244f   /* 0.125 * log2(e) : scores in log2 domain */
#else
#define EXPFN(x) __expf(x)
#define QSCALE 0.125f
#endif

static __device__ __forceinline__ short bfb(float f) {
  union { __hip_bfloat16 h; short s; } u;
  u.h = __float2bfloat16(f);
  return u.s;
}

// async global->LDS, 16 bytes per lane. lds must be wave-uniform.
static __device__ __forceinline__ void gload_lds16(const __hip_bfloat16* g, __hip_bfloat16* lds) {
  __builtin_amdgcn_global_load_lds(
      (const __attribute__((address_space(1))) unsigned int*)g,
      (__attribute__((address_space(3))) unsigned int*)lds, 16, 0, 0);
}

// K granule swizzle (16B granules, 8 per 128B row): rows 8a+b -> (a+2b)&7
static __device__ __forceinline__ int swzg(int row) {
  return (((row >> 3) & 3) + 2 * (row & 3)) & 7;
}

// ---------------- fused fp32->bf16 convert (x, Wq, Wo) + rope table + queue reset ----------------
#define XN4 (NT * DM / 4)          // 786432
#define WQN4 (E3 * DM / 4)         // 442368
#define WON4 (DM * DM / 4)         // 147456
#define CVT_N (XN4 + WQN4 + WON4)  // 1376256
__global__ void cvt3_rope(const float* __restrict__ x, const float* __restrict__ wq,
                          const float* __restrict__ wo,
                          __hip_bfloat16* __restrict__ xb, __hip_bfloat16* __restrict__ wqb,
                          __hip_bfloat16* __restrict__ wob, float2* __restrict__ rcs,
                          int* __restrict__ qcnt) {
  int i = blockIdx.x * blockDim.x + threadIdx.x;
  if (blockIdx.x == 0 && threadIdx.x < 8) qcnt[threadIdx.x] = 0;  // per-XCD LPT queues
  if (i >= CVT_N) {
    int idx = i - CVT_N;
    if (idx < SEQ * 32) {
      int pos = idx >> 5, j = idx & 31;
      float freq = __expf(-(float)j * (logf(10000.0f) / 32.0f));
      float ang = (float)pos * freq;
      rcs[idx] = make_float2(cosf(ang), sinf(ang));
    }
    return;
  }
  const float* src;
  __hip_bfloat16* dst;
  int k;
  if (i < XN4) { src = x; dst = xb; k = i; }
  else if (i < XN4 + WQN4) { src = wq; dst = wqb; k = i - XN4; }
  else { src = wo; dst = wob; k = i - XN4 - WQN4; }
  floatx4 v = ((const floatx4*)src)[k];
  short4v o;
  o[0] = bfb(v[0]); o[1] = bfb(v[1]); o[2] = bfb(v[2]); o[3] = bfb(v[3]);
  ((short4v*)dst)[k] = o;
}

// ---------------- QKV GEMM v4: 64x128 tile, BK=64, double-buffered (R19) ----------------
__global__ __launch_bounds__(256) void qkv_gemm_rope(
    const __hip_bfloat16* __restrict__ Wq,
    const __hip_bfloat16* __restrict__ Xb,
    const int* __restrict__ tpos,
    const float2* __restrict__ rcs,
    __hip_bfloat16* __restrict__ Qb, __hip_bfloat16* __restrict__ Kb,
    __hip_bfloat16* __restrict__ Vt)
{
  __shared__ __align__(16) __hip_bfloat16 As[2][64 * 64];    // 8KB each
  __shared__ __align__(16) __hip_bfloat16 Bs[2][128 * 64];   // 16KB each
  const int tid = threadIdx.x;
  const int lane = tid & 63, w = tid >> 6;
  const int c = lane & 15, g = lane >> 4;
  const int wr = w >> 1, wc = w & 1;
  const int bid = blockIdx.x;
  const int xcd = bid & 7, i_ = bid >> 3;        // 144 per XCD
  const int nb = xcd * 4 + (i_ & 3), mb = i_ >> 2;  // nb 0..31, mb 0..35
  const int m0 = mb * 64, n0 = nb * 128;
  const int srow = tid >> 3, sslot = tid & 7;    // 32 rows x 8 slots per call

#define QKV_STAGE(K0_, AD, BD)                                                      \
  do {                                                                              \
    _Pragma("unroll")                                                               \
    for (int j = 0; j < 2; ++j) {                                                   \
      const int row = j * 32 + srow;                                                \
      const int gs = (sslot ^ (row & 7)) * 8;                                       \
      gload_lds16(Wq + (size_t)(m0 + row) * DM + (K0_) + gs, (AD) + j * 2048 + w * 512); \
    }                                                                               \
    _Pragma("unroll")                                                               \
    for (int j = 0; j < 4; ++j) {                                                   \
      const int row = j * 32 + srow;                                                \
      const int gs = (sslot ^ (row & 7)) * 8;                                       \
      gload_lds16(Xb + (size_t)(n0 + row) * DM + (K0_) + gs, (BD) + j * 2048 + w * 512); \
    }                                                                               \
  } while (0)

  floatx4 acc[2][4] = {};
  QKV_STAGE(0, As[0], Bs[0]);
  int cb = 0;
  for (int k0 = 0; k0 < DM; k0 += 64) {
    if (k0 + 64 < DM) QKV_STAGE(k0 + 64, As[cb ^ 1], Bs[cb ^ 1]);
    __syncthreads();   // drains stage(k0) — issued one full step ago
#pragma unroll
    for (int kk = 0; kk < 2; ++kk) {
      short8v a[2], b[4];
#pragma unroll
      for (int i = 0; i < 2; ++i) {
        const int row = wr * 32 + i * 16 + c;
        a[i] = *(const short8v*)&As[cb][row * 64 + (((kk * 4 + g) ^ (row & 7)) * 8)];
      }
#pragma unroll
      for (int j = 0; j < 4; ++j) {
        const int row = wc * 64 + j * 16 + c;
        b[j] = *(const short8v*)&Bs[cb][row * 64 + (((kk * 4 + g) ^ (row & 7)) * 8)];
      }
#pragma unroll
      for (int i = 0; i < 2; ++i)
#pragma unroll
        for (int j = 0; j < 4; ++j)
          acc[i][j] = __builtin_amdgcn_mfma_f32_16x16x32_bf16(a[i], b[j], acc[i][j], 0, 0, 0);
    }
    __syncthreads();   // buf[cb] consumed -> reusable for the stage in flight
    cb ^= 1;
  }
#undef QKV_STAGE
#pragma unroll
  for (int i = 0; i < 2; ++i) {
    const int e0 = m0 + wr * 32 + i * 16 + 4 * g;
    const int jj = (e0 & 63) >> 1;
#pragma unroll
    for (int j = 0; j < 4; ++j) {
      const int t = n0 + wc * 64 + j * 16 + c;
      const int b_ = t >> 11, s = t & (SEQ - 1);
      float v0 = acc[i][j][0], v1 = acc[i][j][1], v2 = acc[i][j][2], v3 = acc[i][j][3];
      if (e0 < 2 * DM) {
        const int pos = tpos[t];
        const float2 cs0 = rcs[pos * 32 + jj];
        const float2 cs1 = rcs[pos * 32 + jj + 1];
        const float n0v = v0 * cs0.x - v1 * cs0.y, n1v = v0 * cs0.y + v1 * cs0.x;
        const float n2v = v2 * cs1.x - v3 * cs1.y, n3v = v2 * cs1.y + v3 * cs1.x;
        v0 = n0v; v1 = n1v; v2 = n2v; v3 = n3v;
      }
      if (e0 < DM) {
        const int h = e0 >> 6, d = e0 & 63;
        short4v pk;
        pk[0] = bfb(v0 * QSCALE); pk[1] = bfb(v1 * QSCALE);
        pk[2] = bfb(v2 * QSCALE); pk[3] = bfb(v3 * QSCALE);
        *(short4v*)&Qb[(((size_t)(b_ * NH + h) * SEQ) + s) * HD + d] = pk;
      } else if (e0 < 2 * DM) {
        const int e = e0 - DM, h = e >> 6, d = e & 63;
        short4v pk;
        pk[0] = bfb(v0); pk[1] = bfb(v1); pk[2] = bfb(v2); pk[3] = bfb(v3);
        *(short4v*)&Kb[(((size_t)(b_ * NH + h) * SEQ) + s) * HD + d] = pk;
      } else {
        const int e = e0 - 2 * DM, h = e >> 6, d = e & 63;
        const size_t base = ((size_t)(b_ * NH + h) * HD + d) * SEQ + s;
        Vt[base]           = __float2bfloat16(v0);
        Vt[base + SEQ]     = __float2bfloat16(v1);
        Vt[base + 2 * SEQ] = __float2bfloat16(v2);
        Vt[base + 3 * SEQ] = __float2bfloat16(v3);
      }
    }
  }
}

// ---------------- fused causal flash attention v13 (best-known: ~27us) ----------------
// 8 waves x 16 q-rows, KVBLK=128, LPT work queue, setprio, peeled fast path.
// Measured local optimum: v14 (2-frag) and v15 (l-sum MFMA) both regressed.
__global__ __launch_bounds__(512) void attn_fused(
    const __hip_bfloat16* __restrict__ Qb,
    const __hip_bfloat16* __restrict__ Kb,
    const __hip_bfloat16* __restrict__ Vt,
    __hip_bfloat16* __restrict__ Cx,
    int* __restrict__ qcnt)
{
  __shared__ __align__(16) __hip_bfloat16 Ks[2][128 * 64];  // 16KB each
  __shared__ __align__(16) __hip_bfloat16 Vs[2][64 * 128];  // V^T: [d][kt], 16KB each
  __shared__ int task_s;
  const int tid = threadIdx.x;
  const int lane = tid & 63, w = tid >> 6;          // 8 waves
  const int c = lane & 15, g = lane >> 4;
  const int xcd = blockIdx.x & 7;
  const int kr1 = 8 * (c >> 2) + (c & 3);           // permuted A-row -> kt_local
  const int ksr = w * 8 + (lane >> 3), kss = lane & 7;     // K stage: rows +64*j
  const int vsr = w * 4 + (lane >> 4), vss = lane & 15;    // V stage: rows +32*j

  for (;;) {
    if (tid == 0) task_s = atomicAdd(&qcnt[xcd], 1);
    __syncthreads();
    const int task = task_s;
    if (task >= 48) return;
    const int qG = 15 - task / 3;                   // descending size (LPT)
    const int bh = xcd + 8 * (task % 3);
    const int KBmax = qG;                           // kb = 0..qG (128 keys each)
    const __hip_bfloat16* Qh = Qb + (size_t)bh * SEQ * HD;
    const __hip_bfloat16* Kh = Kb + (size_t)bh * SEQ * HD;
    const __hip_bfloat16* Vh = Vt + (size_t)bh * HD * SEQ;
    const int q1 = qG * 128 + w * 16 + c;           // absolute q-row of this lane
    const int qrl32 = (w & 1) * 16 + c;             // row within the diagonal 32-key window
    const int sdiag = w >> 1;                       // wave's diagonal sub-block (in kb==KBmax)
    const short8v qf10 = *(const short8v*)&Qh[(size_t)q1 * HD + g * 8];
    const short8v qf11 = *(const short8v*)&Qh[(size_t)q1 * HD + 32 + g * 8];
    floatx4 o1[4] = {};
    float l1 = 0.0f;

#define STAGE_KV(KB_, KSD, VSD)                                                      \
    do {                                                                             \
      _Pragma("unroll")                                                              \
      for (int j = 0; j < 2; ++j) {                                                  \
        const int kr = j * 64 + ksr;                                                 \
        gload_lds16(Kh + (size_t)((KB_) * 128 + kr) * HD + ((kss ^ swzg(kr)) * 8),   \
                    (KSD) + j * 4096 + w * 512);                                     \
        const int vr = j * 32 + vsr;                                                 \
        gload_lds16(Vh + (size_t)vr * SEQ + (KB_) * 128 + ((vss ^ (vr & 15)) * 8),   \
                    (VSD) + j * 4096 + w * 512);                                     \
      }                                                                              \
    } while (0)

// one 32-key sub-block: QK (setprio-wrapped), optional mask, exp, PV
#define SUBBLK(S_, DO_MASK)                                                          \
    do {                                                                             \
      const int r0 = (S_) * 32 + kr1, r1 = r0 + 4;                                   \
      const int z0 = swzg(r0), z1 = swzg(r1);                                        \
      const short8v a00 = *(const short8v*)&Kt[r0 * 64 + ((g ^ z0) * 8)];            \
      const short8v a01 = *(const short8v*)&Kt[r0 * 64 + (((4 + g) ^ z0) * 8)];      \
      const short8v a10 = *(const short8v*)&Kt[r1 * 64 + ((g ^ z1) * 8)];            \
      const short8v a11 = *(const short8v*)&Kt[r1 * 64 + (((4 + g) ^ z1) * 8)];      \
      short8v vf[4];                                                                 \
      _Pragma("unroll")                                                              \
      for (int f = 0; f < 4; ++f) {                                                  \
        const int rv = f * 16 + c;                                                   \
        vf[f] = *(const short8v*)&Vb[rv * 128 + ((((S_) * 4 + g) ^ (rv & 15)) * 8)]; \
      }                                                                              \
      floatx4 s1a = {}, s1b = {};                                                    \
      __builtin_amdgcn_s_setprio(1);                                                 \
      s1a = __builtin_amdgcn_mfma_f32_16x16x32_bf16(a00, qf10, s1a, 0, 0, 0);        \
      s1a = __builtin_amdgcn_mfma_f32_16x16x32_bf16(a01, qf11, s1a, 0, 0, 0);        \
      s1b = __builtin_amdgcn_mfma_f32_16x16x32_bf16(a10, qf10, s1b, 0, 0, 0);        \
      s1b = __builtin_amdgcn_mfma_f32_16x16x32_bf16(a11, qf11, s1b, 0, 0, 0);        \
      __builtin_amdgcn_s_setprio(0);                                                 \
      if (DO_MASK) {                                                                 \
        _Pragma("unroll")                                                            \
        for (int r = 0; r < 4; ++r) {                                                \
          if (8 * g + r > qrl32) s1a[r] = -INFINITY;                                 \
          if (8 * g + r + 4 > qrl32) s1b[r] = -INFINITY;                             \
        }                                                                            \
      }                                                                              \
      short8v pf1;                                                                   \
      _Pragma("unroll")                                                              \
      for (int r = 0; r < 4; ++r) {                                                  \
        float p;                                                                     \
        p = EXPFN(s1a[r]); l1 += p; pf1[r] = bfb(p);                                 \
        p = EXPFN(s1b[r]); l1 += p; pf1[r + 4] = bfb(p);                             \
      }                                                                              \
      __builtin_amdgcn_s_setprio(1);                                                 \
      o1[0] = __builtin_amdgcn_mfma_f32_16x16x32_bf16(vf[0], pf1, o1[0], 0, 0, 0);   \
      o1[1] = __builtin_amdgcn_mfma_f32_16x16x32_bf16(vf[1], pf1, o1[1], 0, 0, 0);   \
      o1[2] = __builtin_amdgcn_mfma_f32_16x16x32_bf16(vf[2], pf1, o1[2], 0, 0, 0);   \
      o1[3] = __builtin_amdgcn_mfma_f32_16x16x32_bf16(vf[3], pf1, o1[3], 0, 0, 0);   \
      __builtin_amdgcn_s_setprio(0);                                                 \
    } while (0)

    STAGE_KV(0, Ks[0], Vs[0]);
    __syncthreads();
    int cb = 0;
    for (int kb = 0; kb <= KBmax; ++kb) {
      if (kb < KBmax) STAGE_KV(kb + 1, Ks[cb ^ 1], Vs[cb ^ 1]);
      {
        const __hip_bfloat16* Kt = Ks[cb];
        const __hip_bfloat16* Vb = Vs[cb];
        if (kb < KBmax) {
          // fast path: every sub-block fully causal for every wave — branch-free.
          SUBBLK(0, false);
          SUBBLK(1, false);
          SUBBLK(2, false);
          SUBBLK(3, false);
        } else {
          // tail: wave w computes sub-blocks s < sdiag unmasked, s == sdiag masked.
#pragma unroll
          for (int s = 0; s < 4; ++s) {
            if (s < sdiag) SUBBLK(s, false);
            else if (s == sdiag) SUBBLK(s, true);
          }
        }
      }
      __syncthreads();
      cb ^= 1;
    }
#undef SUBBLK
#undef STAGE_KV

    l1 += __shfl_xor(l1, 16); l1 += __shfl_xor(l1, 32);
    const float inv1 = 1.0f / l1;
    const int bb = bh / NH, h = bh - bb * NH;
    const size_t trow1 = ((size_t)bb * SEQ + q1) * DM + (size_t)h * HD;
#pragma unroll
    for (int f = 0; f < 4; ++f) {
      short4v pk1;
#pragma unroll
      for (int r = 0; r < 4; ++r) pk1[r] = bfb(o1[f][r] * inv1);
      *(short4v*)&Cx[trow1 + f * 16 + 4 * g] = pk1;
    }
  }
}

// ---------------- output GEMM v3: 64x128 tile, BK=64, double-buffered (R19) ----------------
__global__ __launch_bounds__(256) void out_gemm(
    const __hip_bfloat16* __restrict__ Wo,
    const __hip_bfloat16* __restrict__ Cx,
    float* __restrict__ out)
{
  __shared__ __align__(16) __hip_bfloat16 As[2][64 * 64];    // 8KB each
  __shared__ __align__(16) __hip_bfloat16 Bs[2][128 * 64];   // 16KB each
  const int tid = threadIdx.x;
  const int lane = tid & 63, w = tid >> 6;
  const int c = lane & 15, g = lane >> 4;
  const int wr = w >> 1, wc = w & 1;
  const int bid = blockIdx.x;
  const int xcd = bid & 7, i_ = bid >> 3;        // 48 per XCD
  const int nb = xcd * 4 + (i_ & 3), mb = i_ >> 2;  // nb 0..31 (t), mb 0..11 (e)
  const int m0 = mb * 64, n0 = nb * 128;
  const int srow = tid >> 3, sslot = tid & 7;

#define OUT_STAGE(K0_, AD, BD)                                                      \
  do {                                                                              \
    _Pragma("unroll")                                                               \
    for (int j = 0; j < 2; ++j) {                                                   \
      const int row = j * 32 + srow;                                                \
      const int gs = (sslot ^ (row & 7)) * 8;                                       \
      gload_lds16(Wo + (size_t)(m0 + row) * DM + (K0_) + gs, (AD) + j * 2048 + w * 512); \
    }                                                                               \
    _Pragma("unroll")                                                               \
    for (int j = 0; j < 4; ++j) {                                                   \
      const int row = j * 32 + srow;                                                \
      const int gs = (sslot ^ (row & 7)) * 8;                                       \
      gload_lds16(Cx + (size_t)(n0 + row) * DM + (K0_) + gs, (BD) + j * 2048 + w * 512); \
    }                                                                               \
  } while (0)

  floatx4 acc[2][4] = {};
  OUT_STAGE(0, As[0], Bs[0]);
  int cb = 0;
  for (int k0 = 0; k0 < DM; k0 += 64) {
    if (k0 + 64 < DM) OUT_STAGE(k0 + 64, As[cb ^ 1], Bs[cb ^ 1]);
    __syncthreads();
#pragma unroll
    for (int kk = 0; kk < 2; ++kk) {
      short8v a[2], b[4];
#pragma unroll
      for (int i = 0; i < 2; ++i) {
        const int row = wr * 32 + i * 16 + c;
        a[i] = *(const short8v*)&As[cb][row * 64 + (((kk * 4 + g) ^ (row & 7)) * 8)];
      }
#pragma unroll
      for (int j = 0; j < 4; ++j) {
        const int row = wc * 64 + j * 16 + c;
        b[j] = *(const short8v*)&Bs[cb][row * 64 + (((kk * 4 + g) ^ (row & 7)) * 8)];
      }
#pragma unroll
      for (int i = 0; i < 2; ++i)
#pragma unroll
        for (int j = 0; j < 4; ++j)
          acc[i][j] = __builtin_amdgcn_mfma_f32_16x16x32_bf16(a[i], b[j], acc[i][j], 0, 0, 0);
    }
    __syncthreads();
    cb ^= 1;
  }
#undef OUT_STAGE
#pragma unroll
  for (int i = 0; i < 2; ++i) {
    const int e0 = m0 + wr * 32 + i * 16 + 4 * g;
#pragma unroll
    for (int j = 0; j < 4; ++j) {
      const int t = n0 + wc * 64 + j * 16 + c;
      *(floatx4*)&out[(size_t)t * DM + e0] = acc[i][j];
    }
  }
}

extern "C" void kernel_launch(void* const* d_in, const int* in_sizes, int n_in,
                              void* d_out, int out_size, void* d_ws, size_t ws_size,
                              hipStream_t stream) {
  const float* x    = (const float*)d_in[0];
  const int*   tpos = (const int*)d_in[1];
  const float* Wq   = (const float*)d_in[2];
  const float* Wo   = (const float*)d_in[3];
  float* out = (float*)d_out;

  const size_t QKV_BYTES = (size_t)NB * NH * SEQ * HD * 2;  // 6,291,456
  const size_t REQUIRED = 4 * QKV_BYTES;                    // 25,165,824
  if (ws_size < REQUIRED) return;

  char* ws = (char*)d_ws;
  __hip_bfloat16* Qb = (__hip_bfloat16*)(ws);
  __hip_bfloat16* Kb = (__hip_bfloat16*)(ws + QKV_BYTES);
  __hip_bfloat16* Vt = (__hip_bfloat16*)(ws + 2 * QKV_BYTES);
  __hip_bfloat16* Cx = (__hip_bfloat16*)(ws + 3 * QKV_BYTES);
  __hip_bfloat16* xb = (__hip_bfloat16*)(ws + 3 * QKV_BYTES);   // aliases Cx (dead before attn)
  char* ob = (char*)d_out;   // d_out-head scratch, all dead before out_gemm overwrites
  float2* rcs = (float2*)(ob);                                           // 512KB
  __hip_bfloat16* wqb = (__hip_bfloat16*)(ob + (size_t)SEQ * 32 * 8);    // 3.54MB
  __hip_bfloat16* wob = (__hip_bfloat16*)(ob + (size_t)SEQ * 32 * 8 + (size_t)E3 * DM * 2);  // 1.18MB
  int* qcnt = (int*)(ob + (size_t)SEQ * 32 * 8 + (size_t)E3 * DM * 2 + (size_t)DM * DM * 2); // 32B

  const int TOT_N = CVT_N + SEQ * 32;
  cvt3_rope<<<dim3((TOT_N + 255) / 256), dim3(256), 0, stream>>>(x, Wq, Wo, xb, wqb, wob, rcs, qcnt);
  qkv_gemm_rope<<<dim3(1152), dim3(256), 0, stream>>>(wqb, xb, tpos, rcs, Qb, Kb, Vt);
  attn_fused<<<dim3(512), dim3(512), 0, stream>>>(Qb, Kb, Vt, Cx, qcnt);
  out_gemm<<<dim3(384), dim3(256), 0, stream>>>(wob, Cx, out);
}